// Round 2
// baseline (1569.700 us; speedup 1.0000x reference)
//
#include <hip/hip_runtime.h>

// LSTM: T=4096, B=512, NIN=42, NH=9.
// proj: P[row][j*4+g] = x[row]·W_ih[g*9+j] + b_ih + b_hh  (gate-permuted quads).
//       x staged in LDS (coalesced float4); W_ih staged gate-permuted in LDS once per
//       block and read wave-uniform via ds_read_b128 (broadcast, conflict-free) --
//       replaces the old s_load path that was scalar-mem latency bound.
// lstm: 512 chains; 16 lanes/chain (9 active), 4 chains per 64-thread block.
//       h exchange via DPP row_ror rotations (VALU, ~4cy) instead of ds_swizzle
//       (LDS pipe, ~120cy serially exposed every step). Weights pre-rotated and
//       zero-padded per lane so register indices stay uniform. 8-deep P prefetch ring.
// d_ws: P = 4096*512*36 floats = 301,989,888 bytes.

#define TT 4096
#define BB 512
#define NIN 42
#define NH 9
#define G4 36
#define PF 8

typedef float v2f __attribute__((ext_vector_type(2)));

__device__ __forceinline__ float fast_sigmoid(float x) {
  float e = __builtin_amdgcn_exp2f(-1.4426950408889634f * x);
  return __builtin_amdgcn_rcpf(1.0f + e);
}
__device__ __forceinline__ float fast_tanh(float x) {
  float e = __builtin_amdgcn_exp2f(2.8853900817779268f * x);
  return 1.0f - 2.0f * __builtin_amdgcn_rcpf(1.0f + e);
}

// rotate-right within each 16-lane row: dst lane n gets src lane (n-S)&15.
// DPP row_ror encoding = 0x120+S; all-immediate args as required.
#define ROR16(dst, src, S)                                                     \
  dst = __int_as_float(__builtin_amdgcn_update_dpp(                            \
      0, __float_as_int(src), 0x120 + (S), 0xF, 0xF, true))

__global__ __launch_bounds__(256) void proj_kernel(
    const float* __restrict__ x, const float* __restrict__ W_ih,
    const float* __restrict__ b_ih, const float* __restrict__ b_hh,
    float* __restrict__ P) {
  __shared__ float xs[256 * NIN];   // 43008 B
  __shared__ float ws[NIN * G4];    // 6048 B: ws[k*36 + (j*4+g)] = W_ih[(g*9+j)*42+k]
  const int tid = threadIdx.x;
  const size_t rowBase = (size_t)blockIdx.x * 256;

  // ---- stage W gate-permuted (1512 floats, once per block) ----
  for (int idx = tid; idx < NIN * G4; idx += 256) {
    int k = idx / G4;
    int m = idx - k * G4;
    int j = m >> 2, g = m & 3;
    ws[idx] = W_ih[(g * NH + j) * NIN + k];
  }

  // ---- stage x: 2688 float4 per block, fully coalesced ----
  const float4* xv4 = (const float4*)(x + rowBase * NIN);
  float4* xs4 = (float4*)xs;
#pragma unroll
  for (int it = 0; it < 11; ++it) {
    int idx = tid + it * 256;
    if (idx < 2688) xs4[idx] = xv4[idx];
  }
  __syncthreads();

  // ---- compute: one row per thread ----
  float acc[G4];
#pragma unroll
  for (int m = 0; m < G4; m++) {
    int j = m >> 2, g = m & 3;
    acc[m] = b_ih[g * NH + j] + b_hh[g * NH + j];  // uniform -> scalar loads (init only)
  }

  // pull this thread's x row into registers
  const float* xr = xs + tid * NIN;
  float xv[NIN];
#pragma unroll
  for (int k = 0; k < NIN; k++) xv[k] = xr[k];

#pragma unroll
  for (int k = 0; k < NIN; k++) {
    float xk = xv[k];
    const float4* wv = (const float4*)(ws + k * G4);  // 144B stride: 16B aligned
#pragma unroll
    for (int q = 0; q < NH; q++) {
      float4 w = wv[q];  // wave-uniform addr -> LDS broadcast, conflict-free
      acc[4 * q + 0] += xk * w.x;
      acc[4 * q + 1] += xk * w.y;
      acc[4 * q + 2] += xk * w.z;
      acc[4 * q + 3] += xk * w.w;
    }
  }

  float4* o = (float4*)(P + (rowBase + tid) * (size_t)G4);
#pragma unroll
  for (int q = 0; q < NH; q++)
    o[q] = make_float4(acc[4 * q], acc[4 * q + 1], acc[4 * q + 2], acc[4 * q + 3]);
}

__global__ __launch_bounds__(64) void lstm_kernel(
    const float* __restrict__ P, const float* __restrict__ h0,
    const float* __restrict__ c0, const float* __restrict__ W_hh,
    float* __restrict__ out) {
  const int lane = threadIdx.x;
  const int cl = lane >> 4;
  const int j = lane & 15;
  const bool act = (j < NH);
  const int jj = act ? j : 0;
  const int b = blockIdx.x * 4 + cl;

  // Pre-rotated, zero-padded recurrent weights.
  // At rotation step s (row_ror:s), lane j holds h of unit k=(j-s)&15; pair it with
  // W_hh[gate][j][k], or 0 when k is a phantom unit (k>=9) or this lane is inactive.
  v2f Wif[16], Wgo[16];
#pragma unroll
  for (int s = 0; s < 16; s++) {
    int k = (j - s) & 15;
    int kk = (k < NH) ? k : 0;            // keep loads in-bounds
    float vm = (act && k < NH) ? 1.f : 0.f;
    Wif[s] = (v2f){vm * W_hh[(0 * NH + jj) * NH + kk],
                   vm * W_hh[(1 * NH + jj) * NH + kk]};
    Wgo[s] = (v2f){vm * W_hh[(2 * NH + jj) * NH + kk],
                   vm * W_hh[(3 * NH + jj) * NH + kk]};
  }

  float h = h0[b * NH + jj];
  float c = c0[b * NH + jj];

  const float4* Pv = (const float4*)P;
  const size_t stride = (size_t)BB * NH;  // 4608
  const size_t base = (size_t)b * NH + jj;

  float4 pre[PF];
#pragma unroll
  for (int i = 0; i < PF; i++) pre[i] = Pv[(size_t)i * stride + base];

  for (int t0 = 0; t0 < TT; t0 += PF) {
#pragma unroll
    for (int u = 0; u < PF; u++) {
      const int t = t0 + u;
      float4 p = pre[u];

      // 15 independent VALU-speed rotations of h within this chain's 16-lane row
      float r1, r2, r3, r4, r5, r6, r7, r8, r9, r10, r11, r12, r13, r14, r15;
      ROR16(r1, h, 1);   ROR16(r2, h, 2);   ROR16(r3, h, 3);
      ROR16(r4, h, 4);   ROR16(r5, h, 5);   ROR16(r6, h, 6);
      ROR16(r7, h, 7);   ROR16(r8, h, 8);   ROR16(r9, h, 9);
      ROR16(r10, h, 10); ROR16(r11, h, 11); ROR16(r12, h, 12);
      ROR16(r13, h, 13); ROR16(r14, h, 14); ROR16(r15, h, 15);

      v2f a0 = (v2f){p.x, p.y} + Wif[0] * h;
      v2f a1 = Wif[1] * r1;
      v2f a2 = Wif[2] * r2;
      v2f a3 = Wif[3] * r3;
      a0 += Wif[4] * r4;   a1 += Wif[5] * r5;   a2 += Wif[6] * r6;   a3 += Wif[7] * r7;
      a0 += Wif[8] * r8;   a1 += Wif[9] * r9;   a2 += Wif[10] * r10; a3 += Wif[11] * r11;
      a0 += Wif[12] * r12; a1 += Wif[13] * r13; a2 += Wif[14] * r14; a3 += Wif[15] * r15;
      v2f gif = (a0 + a1) + (a2 + a3);

      v2f d0 = (v2f){p.z, p.w} + Wgo[0] * h;
      v2f d1 = Wgo[1] * r1;
      v2f d2 = Wgo[2] * r2;
      v2f d3 = Wgo[3] * r3;
      d0 += Wgo[4] * r4;   d1 += Wgo[5] * r5;   d2 += Wgo[6] * r6;   d3 += Wgo[7] * r7;
      d0 += Wgo[8] * r8;   d1 += Wgo[9] * r9;   d2 += Wgo[10] * r10; d3 += Wgo[11] * r11;
      d0 += Wgo[12] * r12; d1 += Wgo[13] * r13; d2 += Wgo[14] * r14; d3 += Wgo[15] * r15;
      v2f ggo = (d0 + d1) + (d2 + d3);

      float i_ = fast_sigmoid(gif.x);
      float f_ = fast_sigmoid(gif.y);
      float g_ = fast_tanh(ggo.x);
      float o_ = fast_sigmoid(ggo.y);
      c = f_ * c + i_ * g_;
      h = o_ * fast_tanh(c);
      if (act) out[(size_t)t * stride + base] = h;

      int tn = t + PF;                 // prefetch (clamped; tail unused)
      if (tn > TT - 1) tn = TT - 1;
      pre[u] = Pv[(size_t)tn * stride + base];
    }
  }

  if (act) {
    out[(size_t)TT * stride + (size_t)b * NH + j] = h;                    // hn
    out[(size_t)TT * stride + stride + (size_t)b * NH + j] = c;           // cn
  }
}

extern "C" void kernel_launch(void* const* d_in, const int* in_sizes, int n_in,
                              void* d_out, int out_size, void* d_ws, size_t ws_size,
                              hipStream_t stream) {
  (void)in_sizes; (void)n_in; (void)out_size; (void)ws_size;
  const float* x    = (const float*)d_in[0];
  const float* h0   = (const float*)d_in[1];
  const float* c0   = (const float*)d_in[2];
  const float* W_ih = (const float*)d_in[3];
  const float* W_hh = (const float*)d_in[4];
  const float* b_ih = (const float*)d_in[5];
  const float* b_hh = (const float*)d_in[6];
  float* out = (float*)d_out;
  float* P   = (float*)d_ws;  // 302 MB workspace

  proj_kernel<<<(TT * BB) / 256, 256, 0, stream>>>(x, W_ih, b_ih, b_hh, P);
  lstm_kernel<<<BB / 4, 64, 0, stream>>>(P, h0, c0, W_hh, out);
}